// Round 3
// baseline (456.187 us; speedup 1.0000x reference)
//
#include <hip/hip_runtime.h>

typedef __bf16 bf16x8 __attribute__((ext_vector_type(8)));
typedef float f32x4 __attribute__((ext_vector_type(4)));

namespace {
constexpr int kCZ = 1, kCY = 400, kCX = 352;
constexpr int kCL = 2 * kCZ * kCY * kCX;  // 281600 voxels
constexpr float kVX = 0.2f, kVY = 0.2f, kVZ = 4.0f;
constexpr float kXOFF = 0.1f;    // VX/2 + X0
constexpr float kYOFF = -39.9f;  // VY/2 + Y0
constexpr float kZOFF = -1.0f;   // VZ/2 + Z0
}

__device__ __forceinline__ float bf2f(unsigned short u) {
  return __uint_as_float(((unsigned int)u) << 16);
}
__device__ __forceinline__ unsigned short f2bf(float f) {
  unsigned int u = __float_as_uint(f);
  u += 0x7fffu + ((u >> 16) & 1u);  // RNE
  return (unsigned short)(u >> 16);
}

union BF8 { unsigned short u[8]; bf16x8 v; };

// Split f32 -> (hi, lo) bf16 pair: v ~= bf(hi) + bf(lo), residual ~2^-18 |v|
__device__ __forceinline__ void split_bf(float v, unsigned short& h,
                                         unsigned short& l) {
  h = f2bf(v);
  l = f2bf(v - bf2f(h));
}

// Componentwise max of two packed non-negative bf16 values via 32-bit CAS.
// Init 0; ReLU outputs are >=0 so uint16 compare == bf16 compare.
__device__ __forceinline__ void atomic_max_bf16pair(unsigned int* addr,
                                                    unsigned int val) {
  if (val == 0u) return;
  unsigned int cur = atomicCAS(addr, 0u, val);
  while (cur != 0u) {
    unsigned short clo = (unsigned short)(cur & 0xffffu);
    unsigned short chi = (unsigned short)(cur >> 16);
    unsigned short vlo = (unsigned short)(val & 0xffffu);
    unsigned short vhi = (unsigned short)(val >> 16);
    unsigned int mrg = (unsigned int)(clo > vlo ? clo : vlo) |
                       ((unsigned int)(chi > vhi ? chi : vhi) << 16);
    if (mrg == cur) return;
    unsigned int prev = atomicCAS(addr, cur, mrg);
    if (prev == cur) return;
    cur = prev;
  }
}

// ---------------- K1: per-voxel xyz-sum + count ----------------
__global__ void k_count(const float4* __restrict__ feat,
                        const int4* __restrict__ coors,
                        float* __restrict__ sums, int n) {
  int p = blockIdx.x * blockDim.x + threadIdx.x;
  if (p >= n) return;
  int4 c = coors[p];  // [b, z, y, x]
  int idx = ((c.x * kCZ + c.y) * kCY + c.z) * kCX + c.w;
  float4 f = feat[p];
  float* s = sums + 4LL * idx;
  atomicAdd(s + 0, f.x);
  atomicAdd(s + 1, f.y);
  atomicAdd(s + 2, f.z);
  atomicAdd(s + 3, 1.0f);
}

struct PointFeats {
  float v0[8];
  float v1[3];
  int idx;
};

__device__ __forceinline__ PointFeats compute_feats(int p,
    const float4* __restrict__ feat, const int4* __restrict__ coors,
    const float4* __restrict__ sums) {
  int4 c = coors[p];
  int idx = ((c.x * kCZ + c.y) * kCY + c.z) * kCX + c.w;
  float4 f = feat[p];
  float fx = f.x, fy = f.y, fz = f.z, fr = f.w;
  float4 s = sums[idx];
  float rc = 1.0f / fmaxf(s.w, 1.0f);
  float clx = fx - s.x * rc, cly = fy - s.y * rc, clz = fz - s.z * rc;
  float cex = fx - ((float)c.w * kVX + kXOFF);
  float cey = fy - ((float)c.z * kVY + kYOFF);
  float cez = fz - ((float)c.y * kVZ + kZOFF);
  float dist = sqrtf(fx * fx + fy * fy + fz * fz);
  PointFeats r;
  r.v0[0] = fx;  r.v0[1] = fy;  r.v0[2] = fz;  r.v0[3] = fr;
  r.v0[4] = clx; r.v0[5] = cly; r.v0[6] = clz; r.v0[7] = cex;
  r.v1[0] = cey; r.v1[1] = cez; r.v1[2] = dist;
  r.idx = idx;
  return r;
}

// Split A-fragments for 16x16x32 bf16: lane holds A[m=lane&15][k=q*8+i]
__device__ __forceinline__ void build_a1(const PointFeats& pf, int q,
                                         BF8& ah, BF8& al) {
#pragma unroll
  for (int i = 0; i < 8; ++i) {
    float v = 0.0f;
    if (q == 0) v = pf.v0[i];
    else if (q == 1) v = (i < 3) ? pf.v1[i] : 0.0f;
    split_bf(v, ah.u[i], al.u[i]);
  }
}

// GEMM accumulate with split operands: c += (ah+al)*(bh+bl), drop al*bl
__device__ __forceinline__ f32x4 mfma_split(const BF8& ah, const BF8& al,
                                            const BF8& bh, const BF8& bl,
                                            f32x4 c) {
  c = __builtin_amdgcn_mfma_f32_16x16x32_bf16(ah.v, bh.v, c, 0, 0, 0);
  c = __builtin_amdgcn_mfma_f32_16x16x32_bf16(al.v, bh.v, c, 0, 0, 0);
  c = __builtin_amdgcn_mfma_f32_16x16x32_bf16(ah.v, bl.v, c, 0, 0, 0);
  return c;
}

// ---------------- K2: pf1 = relu(feats@W1*s1+sh1) -> pair-max vmax1 ----
__global__ void k_stage1(const float4* __restrict__ feat,
                         const int4* __restrict__ coors,
                         const float4* __restrict__ sums,
                         const float* __restrict__ W1,
                         const float* __restrict__ scale1,
                         const float* __restrict__ shift1,
                         unsigned int* __restrict__ vmax1, int n) {
  int t = threadIdx.x;
  int lane = t & 63;
  int wv = t >> 6;            // 4 waves = 4 column tiles of 16
  int m = lane & 15, q = lane >> 4;
  int col = wv * 16 + m;      // output column 0..63
  BF8 b1h, b1l;
#pragma unroll
  for (int i = 0; i < 8; ++i) {
    int k = q * 8 + i;
    float w = (k < 11) ? W1[k * 64 + col] : 0.0f;
    split_bf(w, b1h.u[i], b1l.u[i]);
  }
  float s1 = scale1[col], sh1 = shift1[col];
  int ngroups = (n + 15) >> 4;
  for (int g = blockIdx.x; g < ngroups; g += gridDim.x) {
    int p0 = g * 16;
    int p = min(p0 + m, n - 1);
    PointFeats pfv = compute_feats(p, feat, coors, sums);
    BF8 a1h, a1l;
    build_a1(pfv, q, a1h, a1l);
    f32x4 c1 = {0.f, 0.f, 0.f, 0.f};
    c1 = mfma_split(a1h, a1l, b1h, b1l, c1);
    // epilogue: relu(c*s+sh), pack adjacent cols, CAS-max into vmax1
    float vr[4], ur[4];
#pragma unroll
    for (int r = 0; r < 4; ++r) vr[r] = fmaxf(c1[r] * s1 + sh1, 0.0f);
#pragma unroll
    for (int r = 0; r < 4; ++r) ur[r] = __shfl_xor(vr[r], 1);
    int rbase = (lane & 1) * 2;
    int pcol = col >> 1;
#pragma unroll
    for (int rr = 0; rr < 2; ++rr) {
      int r = rbase + rr;
      int row = q * 4 + r;
      float lo = (lane & 1) ? ur[r] : vr[r];
      float hi = (lane & 1) ? vr[r] : ur[r];
      unsigned int pk = (unsigned int)f2bf(lo) |
                        ((unsigned int)f2bf(hi) << 16);
      int idxr = __shfl(pfv.idx, row);
      if (p0 + row < n)
        atomic_max_bf16pair(vmax1 + (size_t)idxr * 32 + pcol, pk);
    }
  }
}

// ---------------- K3: feats2=[pf1, vmax1[idx]]; pf2 -> f32 max d_out ----
__global__ void k_stage2(const float4* __restrict__ feat,
                         const int4* __restrict__ coors,
                         const float4* __restrict__ sums,
                         const float* __restrict__ W1,
                         const float* __restrict__ scale1,
                         const float* __restrict__ shift1,
                         const float* __restrict__ W2,
                         const float* __restrict__ scale2,
                         const float* __restrict__ shift2,
                         const unsigned int* __restrict__ vmax1,
                         float* __restrict__ out, int n) {
  __shared__ unsigned short A2h[16][132];  // hi bf16 plane, stride 132
  __shared__ unsigned short A2l[16][132];  // lo bf16 plane
  int t = threadIdx.x;
  int lane = t & 63;
  int wv = t >> 6;
  int m = lane & 15, q = lane >> 4;
  int col = wv * 16 + m;
  BF8 b1h, b1l;
#pragma unroll
  for (int i = 0; i < 8; ++i) {
    int k = q * 8 + i;
    float w = (k < 11) ? W1[k * 64 + col] : 0.0f;
    split_bf(w, b1h.u[i], b1l.u[i]);
  }
  BF8 b2h[4], b2l[4];  // W2 fragments, K=128 in 4 k-blocks of 32
#pragma unroll
  for (int kb = 0; kb < 4; ++kb)
#pragma unroll
    for (int i = 0; i < 8; ++i)
      split_bf(W2[(kb * 32 + q * 8 + i) * 64 + col], b2h[kb].u[i],
               b2l[kb].u[i]);
  float s1 = scale1[col], sh1 = shift1[col];
  float s2 = scale2[col], sh2 = shift2[col];
  int tm = t & 15;  // point row for the gather (== m within a wave)
  int jq = t >> 4;  // 0..15 -> 4-column chunk
  // zero the lo-plane for gathered cols 64..127 (exact bf16, lo == 0)
  *(ushort4*)&A2l[t >> 4][64 + (t & 15) * 4] = ushort4{0, 0, 0, 0};
  int ngroups = (n + 15) >> 4;
  for (int g = blockIdx.x; g < ngroups; g += gridDim.x) {
    int p0 = g * 16;
    int p = min(p0 + tm, n - 1);
    PointFeats pfv = compute_feats(p, feat, coors, sums);
    BF8 a1h, a1l;
    build_a1(pfv, q, a1h, a1l);
    f32x4 c1 = {0.f, 0.f, 0.f, 0.f};
    c1 = mfma_split(a1h, a1l, b1h, b1l, c1);
    // pf1 (C-layout) -> LDS in A-operand layout, hi+lo planes (cols 0..63)
#pragma unroll
    for (int r = 0; r < 4; ++r) {
      int row = q * 4 + r;
      float v = fmaxf(c1[r] * s1 + sh1, 0.0f);
      unsigned short h, l;
      split_bf(v, h, l);
      A2h[row][col] = h;
      A2l[row][col] = l;
    }
    // gather vmax1 (bf16-packed) into cols 64..127 of the hi plane
    uint2 g2 = *(const uint2*)(vmax1 + (size_t)pfv.idx * 32 + jq * 2);
    *(uint2*)&A2h[tm][64 + jq * 4] = g2;
    __syncthreads();
    // K=128 split-MFMA chain
    f32x4 c2 = {0.f, 0.f, 0.f, 0.f};
#pragma unroll
    for (int kb = 0; kb < 4; ++kb) {
      const unsigned short* aph = &A2h[m][kb * 32 + q * 8];
      const unsigned short* apl = &A2l[m][kb * 32 + q * 8];
      BF8 a2h, a2l;
      *(ushort4*)&a2h.u[0] = *(const ushort4*)aph;
      *(ushort4*)&a2h.u[4] = *(const ushort4*)(aph + 4);
      *(ushort4*)&a2l.u[0] = *(const ushort4*)apl;
      *(ushort4*)&a2l.u[4] = *(const ushort4*)(apl + 4);
      c2 = mfma_split(a2h, a2l, b2h[kb], b2l[kb], c2);
    }
    // epilogue: relu(c*s+sh) -> int-punned f32 atomicMax into d_out
#pragma unroll
    for (int r = 0; r < 4; ++r) {
      int row = q * 4 + r;
      if (p0 + row < n) {
        float v = fmaxf(c2[r] * s2 + sh2, 0.0f);
        int idxr = __shfl(pfv.idx, row);
        atomicMax((int*)(out + (size_t)idxr * 64 + col), __float_as_int(v));
      }
    }
    __syncthreads();  // protect A2 before next group
  }
}

extern "C" void kernel_launch(void* const* d_in, const int* in_sizes, int n_in,
                              void* d_out, int out_size, void* d_ws, size_t ws_size,
                              hipStream_t stream) {
  const float4* feat = (const float4*)d_in[0];
  const int4* coors = (const int4*)d_in[1];
  const float* W1 = (const float*)d_in[2];
  const float* scale1 = (const float*)d_in[3];
  const float* shift1 = (const float*)d_in[4];
  const float* W2 = (const float*)d_in[5];
  const float* scale2 = (const float*)d_in[6];
  const float* shift2 = (const float*)d_in[7];
  int n = in_sizes[0] / 4;  // 500000 points

  // Workspace (40.55 MB): sums[CL*4] f32 | vmax1[CL*32] u32 (packed bf16 x2)
  float* sums = (float*)d_ws;
  unsigned int* vmax1 = (unsigned int*)(sums + (size_t)kCL * 4);
  size_t zbytes = (size_t)kCL * 4 * 4 + (size_t)kCL * 32 * 4;
  hipMemsetAsync(d_ws, 0, zbytes, stream);
  hipMemsetAsync(d_out, 0, (size_t)out_size * sizeof(float), stream);

  k_count<<<(n + 255) / 256, 256, 0, stream>>>(feat, coors, sums, n);
  k_stage1<<<4096, 256, 0, stream>>>(feat, coors, (const float4*)sums,
                                     W1, scale1, shift1, vmax1, n);
  k_stage2<<<4096, 256, 0, stream>>>(feat, coors, (const float4*)sums,
                                     W1, scale1, shift1, W2, scale2, shift2,
                                     vmax1, (float*)d_out, n);
}

// Round 4
// 353.199 us; speedup vs baseline: 1.2916x; 1.2916x over previous
//
#include <hip/hip_runtime.h>

typedef __bf16 bf16x8 __attribute__((ext_vector_type(8)));
typedef float f32x4 __attribute__((ext_vector_type(4)));

namespace {
constexpr int kCZ = 1, kCY = 400, kCX = 352;
constexpr int kCL = 2 * kCZ * kCY * kCX;  // 281600 voxels (=1100*256 exactly)
constexpr float kVX = 0.2f, kVY = 0.2f, kVZ = 4.0f;
constexpr float kXOFF = 0.1f;    // VX/2 + X0
constexpr float kYOFF = -39.9f;  // VY/2 + Y0
constexpr float kZOFF = -1.0f;   // VZ/2 + Z0
constexpr int P = 64;            // nominal sorted points per fused block
constexpr int NPmax = 96;        // capacity incl. voxel-straddle extension
constexpr int NBLK = kCL / 256;  // 1100 scan blocks
}

__device__ __forceinline__ float bf2f(unsigned short u) {
  return __uint_as_float(((unsigned int)u) << 16);
}
__device__ __forceinline__ unsigned short f2bf(float f) {
  unsigned int u = __float_as_uint(f);
  u += 0x7fffu + ((u >> 16) & 1u);  // RNE
  return (unsigned short)(u >> 16);
}
__device__ __forceinline__ void split_bf(float v, unsigned short& h,
                                         unsigned short& l) {
  h = f2bf(v);
  l = f2bf(v - bf2f(h));
}

union BF8 { unsigned short u[8]; bf16x8 v; };

__device__ __forceinline__ int voxel_of(int4 c) {
  return ((c.x * kCZ + c.y) * kCY + c.z) * kCX + c.w;
}

// ---------------- histogram: counts per voxel ----------------
__global__ void k_hist(const int4* __restrict__ coors,
                       unsigned int* __restrict__ cnt, int n) {
  int p = blockIdx.x * blockDim.x + threadIdx.x;
  if (p >= n) return;
  atomicAdd(&cnt[voxel_of(coors[p])], 1u);
}

// ---------------- scan level 1: per-block sums ----------------
__global__ void k_scan1(const unsigned int* __restrict__ cnt,
                        unsigned int* __restrict__ bsum) {
  __shared__ unsigned int red[256];
  int t = threadIdx.x;
  red[t] = cnt[blockIdx.x * 256 + t];
  __syncthreads();
  for (int off = 128; off > 0; off >>= 1) {
    if (t < off) red[t] += red[t + off];
    __syncthreads();
  }
  if (t == 0) bsum[blockIdx.x] = red[0];
}

// ---------------- scan level 2: exclusive scan of block sums ----------------
__global__ void k_scan2(const unsigned int* __restrict__ bsum,
                        unsigned int* __restrict__ boff, int nb) {
  __shared__ unsigned int tmp[256];
  __shared__ unsigned int carry;
  int t = threadIdx.x;
  if (t == 0) carry = 0;
  __syncthreads();
  for (int base = 0; base < nb; base += 256) {
    int i = base + t;
    unsigned int v = (i < nb) ? bsum[i] : 0u;
    tmp[t] = v;
    __syncthreads();
    for (int off = 1; off < 256; off <<= 1) {
      unsigned int x = (t >= off) ? tmp[t - off] : 0u;
      __syncthreads();
      tmp[t] += x;
      __syncthreads();
    }
    if (i < nb) boff[i] = carry + tmp[t] - v;
    __syncthreads();
    if (t == 255) carry += tmp[255];
    __syncthreads();
  }
}

// ---------------- scan level 3: full exclusive offsets -> cursor ----------------
__global__ void k_scan3(const unsigned int* __restrict__ cnt,
                        const unsigned int* __restrict__ boff,
                        unsigned int* __restrict__ cursor) {
  __shared__ unsigned int tmp[256];
  int t = threadIdx.x;
  int i = blockIdx.x * 256 + t;
  unsigned int v = cnt[i];
  tmp[t] = v;
  __syncthreads();
  for (int off = 1; off < 256; off <<= 1) {
    unsigned int x = (t >= off) ? tmp[t - off] : 0u;
    __syncthreads();
    tmp[t] += x;
    __syncthreads();
  }
  cursor[i] = boff[blockIdx.x] + tmp[t] - v;
}

// ---------------- scatter: counting-sort point ids by voxel ----------------
__global__ void k_scatter(const int4* __restrict__ coors,
                          unsigned int* __restrict__ cursor,
                          unsigned int* __restrict__ sp,
                          unsigned int* __restrict__ vid2, int n) {
  int p = blockIdx.x * blockDim.x + threadIdx.x;
  if (p >= n) return;
  int v = voxel_of(coors[p]);
  unsigned int pos = atomicAdd(&cursor[v], 1u);
  sp[pos] = (unsigned int)p;
  vid2[pos] = (unsigned int)v;
}

// ---------------- zero-fill empty voxel output rows ----------------
__global__ void k_zero(const unsigned int* __restrict__ cnt,
                       float4* __restrict__ out4) {
  int tid = blockIdx.x * blockDim.x + threadIdx.x;  // kCL*16 threads
  int vox = tid >> 4;
  if (vox >= kCL) return;
  if (cnt[vox] == 0u) out4[tid] = float4{0.f, 0.f, 0.f, 0.f};
}

// ---------------- fused VFE: everything else, zero atomics ----------------
__global__ __launch_bounds__(256, 2) void k_fused(
    const float4* __restrict__ feat,
    const unsigned int* __restrict__ sp,
    const unsigned int* __restrict__ vid2,
    const float* __restrict__ W1,
    const float* __restrict__ scale1, const float* __restrict__ shift1,
    const float* __restrict__ W2,
    const float* __restrict__ scale2, const float* __restrict__ shift2,
    float* __restrict__ out, int n) {
  __shared__ unsigned int gvid[128];     // vid window [i0n-1, i0n+126]
  __shared__ float Fraw[128][4];         // raw features, same window
  __shared__ float F[NPmax][12];         // 11-dim point feats (+pad)
  __shared__ float W1s[704];
  __shared__ float s1s[64], sh1s[64];
  __shared__ unsigned short Ph[NPmax][72], Pl[NPmax][72];  // pf1 hi/lo
  __shared__ unsigned short Vh[NPmax][72], Vl[NPmax][72];  // vmax hi/lo
  __shared__ float Cst[16][68];          // GEMM2 C staging per group
  __shared__ int slot_of[NPmax];
  __shared__ int slot_start[NPmax + 1];
  __shared__ unsigned int slot_vox[NPmax];
  __shared__ float meanv[NPmax][3];
  __shared__ int sA[NPmax + 2];          // voxel-aligned group boundaries
  __shared__ unsigned long long bmask[2];
  __shared__ int sSOFF, sNP, sNS, sNG;

  int t = threadIdx.x;
  long long i0n = (long long)blockIdx.x * P;

  // window loads (gather via sorted point ids) + weights to LDS
  if (t < 128) {
    long long pos = i0n - 1 + t;
    unsigned int v = 0xFFFFFFFFu;
    float4 f = float4{0.f, 0.f, 0.f, 0.f};
    if (pos >= 0 && pos < n) {
      v = vid2[pos];
      f = feat[sp[pos]];
    }
    gvid[t] = v;
    Fraw[t][0] = f.x; Fraw[t][1] = f.y; Fraw[t][2] = f.z; Fraw[t][3] = f.w;
  }
  for (int i = t; i < 704; i += 256) W1s[i] = W1[i];
  if (t < 64) { s1s[t] = scale1[t]; sh1s[t] = shift1[t]; }
  __syncthreads();

  // wave 0: block's voxel-complete point range [i0n+s_off, i0n+ecap)
  if (t < 64) {
    unsigned int prev = gvid[0];
    bool eq = (blockIdx.x > 0) && (gvid[1 + t] == prev);
    unsigned long long m = __ballot(eq);
    int s_off = (~m == 0ull) ? 64 : (__ffsll((long long)(~m)) - 1);
    unsigned int lastv = gvid[P];
    bool eq2 = (1 + P + t < 128) && (lastv != 0xFFFFFFFFu) &&
               (gvid[1 + P + t] == lastv);
    unsigned long long m2 = __ballot(eq2);
    int e_off = __ffsll((long long)(~m2)) - 1;  // bit63 is 0 -> well-defined
    long long ecap = (long long)(P + e_off);
    if (ecap > n - i0n) ecap = n - i0n;
    int np = (int)ecap - s_off;
    if (np > NPmax) np = NPmax;
    if (t == 0) { sSOFF = s_off; sNP = np; }
  }
  __syncthreads();
  int s_off = sSOFF, np = sNP;
  if (np <= 0) return;

  // slot (voxel-run) structure via ballots
  {
    int j = t;
    bool valid = j < np;
    unsigned int vj = valid ? gvid[1 + s_off + j] : 0u;
    bool bf = valid && (j == 0 || vj != gvid[s_off + j]);
    unsigned long long bm = __ballot(bf);
    if ((t & 63) == 0 && t < 128) bmask[t >> 6] = bm;
    __syncthreads();
    if (valid) {
      unsigned long long m0 = bmask[0], m1 = bmask[1];
      int slot;
      if (j < 64) slot = __popcll(m0 << (63 - j)) - 1;
      else slot = __popcll(m0) + __popcll(m1 << (63 - (j - 64))) - 1;
      slot_of[j] = slot;
      if (bf) { slot_start[slot] = j; slot_vox[slot] = vj; }
    }
    if (t == 0) {
      int ns0 = __popcll(bmask[0]) + __popcll(bmask[1]);
      sNS = ns0;
      slot_start[ns0] = np;
    }
  }
  __syncthreads();
  int ns = sNS;

  // per-slot means (t<ns)  ||  voxel-aligned group chain (t==255)
  if (t < ns) {
    int r0 = slot_start[t], r1 = slot_start[t + 1];
    float sx = 0.f, sy = 0.f, sz = 0.f;
    for (int j = r0; j < r1; ++j) {
      sx += Fraw[1 + s_off + j][0];
      sy += Fraw[1 + s_off + j][1];
      sz += Fraw[1 + s_off + j][2];
    }
    float rc = 1.0f / (float)(r1 - r0);
    meanv[t][0] = sx * rc; meanv[t][1] = sy * rc; meanv[t][2] = sz * rc;
  }
  if (t == 255) {
    int g = 0, cur = 0;
    sA[0] = 0;
    while (cur < np) {
      int nxt;
      if (cur + 16 >= np) nxt = np;
      else {
        nxt = slot_start[slot_of[cur + 16]];
        if (nxt <= cur) nxt = cur + 16;  // >16-pt voxel guard (impossible data)
      }
      ++g; sA[g] = nxt; cur = nxt;
    }
    sNG = g;
  }
  __syncthreads();

  // 11-dim features (exact f32)
  if (t < np) {
    int jw = 1 + s_off + t;
    float fx = Fraw[jw][0], fy = Fraw[jw][1], fz = Fraw[jw][2], fr = Fraw[jw][3];
    unsigned int v = gvid[jw];
    unsigned int cx = v % (unsigned int)kCX;
    unsigned int cy = (v / (unsigned int)kCX) % (unsigned int)kCY;
    int s = slot_of[t];
    F[t][0] = fx; F[t][1] = fy; F[t][2] = fz; F[t][3] = fr;
    F[t][4] = fx - meanv[s][0];
    F[t][5] = fy - meanv[s][1];
    F[t][6] = fz - meanv[s][2];
    F[t][7] = fx - ((float)cx * kVX + kXOFF);
    F[t][8] = fy - ((float)cy * kVY + kYOFF);
    F[t][9] = fz - kZOFF;  // cz==0 always (kCZ==1)
    F[t][10] = sqrtf(fx * fx + fy * fy + fz * fz);
    F[t][11] = 0.0f;
  }
  __syncthreads();

  // GEMM1 on VALU (exact f32): pf1 = relu(F@W1*s1+sh1) -> hi/lo bf16 planes
  {
    int col = t & 63, quart = t >> 6;
    float w[11];
#pragma unroll
    for (int k = 0; k < 11; ++k) w[k] = W1s[k * 64 + col];
    float s1 = s1s[col], sh1 = sh1s[col];
    for (int j = quart; j < np; j += 4) {
      float acc = 0.f;
#pragma unroll
      for (int k = 0; k < 11; ++k) acc += F[j][k] * w[k];
      float v = fmaxf(acc * s1 + sh1, 0.0f);
      unsigned short h, l;
      split_bf(v, h, l);
      Ph[j][col] = h; Pl[j][col] = l;
    }
  }
  __syncthreads();

  // per-voxel vmax of pf1 (LDS only, non-atomic)
  {
    int col = t & 63, q2 = t >> 6;
    for (int s = q2; s < ns; s += 4) {
      int r0 = slot_start[s], r1 = slot_start[s + 1];
      float vm = 0.0f;  // pf1 >= 0
      for (int j = r0; j < r1; ++j)
        vm = fmaxf(vm, bf2f(Ph[j][col]) + bf2f(Pl[j][col]));
      unsigned short h, l;
      split_bf(vm, h, l);
      Vh[s][col] = h; Vl[s][col] = l;
    }
  }
  __syncthreads();

  // GEMM2 (MFMA, split-A) per voxel-aligned group of <=16 rows
  int lane = t & 63;
  int wv = t >> 6;
  int m = lane & 15, q = lane >> 4;
  int col = wv * 16 + m;
  BF8 b2h[4];
#pragma unroll
  for (int kb = 0; kb < 4; ++kb)
#pragma unroll
    for (int i = 0; i < 8; ++i)
      b2h[kb].u[i] = f2bf(W2[(kb * 32 + q * 8 + i) * 64 + col]);
  float s2 = scale2[col], sh2 = shift2[col];
  int ng = sNG;
  for (int g = 0; g < ng; ++g) {
    int base = sA[g], lim = sA[g + 1];
    int jj = base + m;
    if (jj > np - 1) jj = np - 1;  // pad rows duplicate last point (ignored)
    int sl = slot_of[jj];
    f32x4 c2 = {0.f, 0.f, 0.f, 0.f};
#pragma unroll
    for (int kb = 0; kb < 4; ++kb) {
      const unsigned short* ph = (kb < 2) ? &Ph[jj][kb * 32 + q * 8]
                                          : &Vh[sl][(kb - 2) * 32 + q * 8];
      const unsigned short* pl = (kb < 2) ? &Pl[jj][kb * 32 + q * 8]
                                          : &Vl[sl][(kb - 2) * 32 + q * 8];
      BF8 ah, al;
      *(ushort4*)&ah.u[0] = *(const ushort4*)ph;
      *(ushort4*)&ah.u[4] = *(const ushort4*)(ph + 4);
      *(ushort4*)&al.u[0] = *(const ushort4*)pl;
      *(ushort4*)&al.u[4] = *(const ushort4*)(pl + 4);
      c2 = __builtin_amdgcn_mfma_f32_16x16x32_bf16(ah.v, b2h[kb].v, c2, 0, 0, 0);
      c2 = __builtin_amdgcn_mfma_f32_16x16x32_bf16(al.v, b2h[kb].v, c2, 0, 0, 0);
    }
#pragma unroll
    for (int r = 0; r < 4; ++r)
      Cst[q * 4 + r][col] = fmaxf(c2[r] * s2 + sh2, 0.0f);
    __syncthreads();
    // per-voxel reduce of this group's rows + direct coalesced global write
    {
      int rcol = t & 63, rq = t >> 6;
      int s_lo = slot_of[base], s_hi = slot_of[lim - 1];
      for (int s = s_lo + rq; s <= s_hi; s += 4) {
        int r0 = max(slot_start[s], base), r1 = min(slot_start[s + 1], lim);
        float mx = 0.0f;
        for (int j = r0; j < r1; ++j) mx = fmaxf(mx, Cst[j - base][rcol]);
        out[(size_t)slot_vox[s] * 64 + rcol] = mx;
      }
    }
    __syncthreads();
  }
}

extern "C" void kernel_launch(void* const* d_in, const int* in_sizes, int n_in,
                              void* d_out, int out_size, void* d_ws, size_t ws_size,
                              hipStream_t stream) {
  const float4* feat = (const float4*)d_in[0];
  const int4* coors = (const int4*)d_in[1];
  const float* W1 = (const float*)d_in[2];
  const float* scale1 = (const float*)d_in[3];
  const float* shift1 = (const float*)d_in[4];
  const float* W2 = (const float*)d_in[5];
  const float* scale2 = (const float*)d_in[6];
  const float* shift2 = (const float*)d_in[7];
  int n = in_sizes[0] / 4;  // 500000 points

  // Workspace (~6.3 MB): cnt[CL] | cursor[CL] | bsum[1104] | boff[1104] |
  //                      sp[N] | vid2[N]
  unsigned int* cnt = (unsigned int*)d_ws;
  unsigned int* cursor = cnt + kCL;
  unsigned int* bsum = cursor + kCL;
  unsigned int* boff = bsum + 1104;
  unsigned int* sp = boff + 1104;
  unsigned int* vid2 = sp + n;
  hipMemsetAsync(cnt, 0, (size_t)kCL * 4, stream);

  k_hist<<<(n + 255) / 256, 256, 0, stream>>>(coors, cnt, n);
  k_scan1<<<NBLK, 256, 0, stream>>>(cnt, bsum);
  k_scan2<<<1, 256, 0, stream>>>(bsum, boff, NBLK);
  k_scan3<<<NBLK, 256, 0, stream>>>(cnt, boff, cursor);
  k_scatter<<<(n + 255) / 256, 256, 0, stream>>>(coors, cursor, sp, vid2, n);
  k_zero<<<kCL * 16 / 256, 256, 0, stream>>>(cnt, (float4*)d_out);
  k_fused<<<(n + P - 1) / P, 256, 0, stream>>>(
      feat, sp, vid2, W1, scale1, shift1, W2, scale2, shift2,
      (float*)d_out, n);
}

// Round 5
// 263.189 us; speedup vs baseline: 1.7333x; 1.3420x over previous
//
#include <hip/hip_runtime.h>

typedef __bf16 bf16x8 __attribute__((ext_vector_type(8)));
typedef float f32x4 __attribute__((ext_vector_type(4)));

namespace {
constexpr int kCX = 352, kCY = 400;
constexpr int kCL = 2 * kCY * kCX;   // 281600 voxels (CZ==1)
constexpr float kVX = 0.2f, kVY = 0.2f;
constexpr float kXOFF = 0.1f;    // VX/2 + X0
constexpr float kYOFF = -39.9f;  // VY/2 + Y0
constexpr float kZOFF = -1.0f;   // VZ/2 + Z0 (cz==0 always)
constexpr int P = 64;            // sorted points per fused block
constexpr int NPmax = 84;        // capacity incl. voxel-straddle extension
constexpr int NBLK = kCL / 256;  // 1100 scan blocks
}

__device__ __forceinline__ float bf2f(unsigned short u) {
  return __uint_as_float(((unsigned int)u) << 16);
}
__device__ __forceinline__ unsigned short f2bf(float f) {
  unsigned int u = __float_as_uint(f);
  u += 0x7fffu + ((u >> 16) & 1u);  // RNE
  return (unsigned short)(u >> 16);
}
__device__ __forceinline__ void split_bf(float v, unsigned short& h,
                                         unsigned short& l) {
  h = f2bf(v);
  l = f2bf(v - bf2f(h));
}

union BF8 { unsigned short u[8]; bf16x8 v; };

__device__ __forceinline__ int voxel_of(int4 c) {
  return ((c.x + c.y) * kCY + c.z) * kCX + c.w;  // CZ==1
}

// ---------------- histogram + vid cache ----------------
__global__ void k_hist(const int4* __restrict__ coors,
                       unsigned int* __restrict__ cnt,
                       unsigned int* __restrict__ vid, int n) {
  int p = blockIdx.x * blockDim.x + threadIdx.x;
  if (p >= n) return;
  int v = voxel_of(coors[p]);
  vid[p] = (unsigned int)v;
  atomicAdd(&cnt[v], 1u);
}

// ---------------- scan level 1: per-block sums ----------------
__global__ void k_scan1(const unsigned int* __restrict__ cnt,
                        unsigned int* __restrict__ bsum) {
  __shared__ unsigned int red[256];
  int t = threadIdx.x;
  red[t] = cnt[blockIdx.x * 256 + t];
  __syncthreads();
  for (int off = 128; off > 0; off >>= 1) {
    if (t < off) red[t] += red[t + off];
    __syncthreads();
  }
  if (t == 0) bsum[blockIdx.x] = red[0];
}

// ---------------- scan level 2: exclusive scan of block sums ----------------
__global__ void k_scan2(const unsigned int* __restrict__ bsum,
                        unsigned int* __restrict__ boff, int nb) {
  __shared__ unsigned int tmp[256];
  __shared__ unsigned int carry;
  int t = threadIdx.x;
  if (t == 0) carry = 0;
  __syncthreads();
  for (int base = 0; base < nb; base += 256) {
    int i = base + t;
    unsigned int v = (i < nb) ? bsum[i] : 0u;
    tmp[t] = v;
    __syncthreads();
    for (int off = 1; off < 256; off <<= 1) {
      unsigned int x = (t >= off) ? tmp[t - off] : 0u;
      __syncthreads();
      tmp[t] += x;
      __syncthreads();
    }
    if (i < nb) boff[i] = carry + tmp[t] - v;
    __syncthreads();
    if (t == 255) carry += tmp[255];
    __syncthreads();
  }
}

// ---------------- scan level 3: full exclusive offsets -> cursor ----------------
__global__ void k_scan3(const unsigned int* __restrict__ cnt,
                        const unsigned int* __restrict__ boff,
                        unsigned int* __restrict__ cursor) {
  __shared__ unsigned int tmp[256];
  int t = threadIdx.x;
  int i = blockIdx.x * 256 + t;
  unsigned int v = cnt[i];
  tmp[t] = v;
  __syncthreads();
  for (int off = 1; off < 256; off <<= 1) {
    unsigned int x = (t >= off) ? tmp[t - off] : 0u;
    __syncthreads();
    tmp[t] += x;
    __syncthreads();
  }
  cursor[i] = boff[blockIdx.x] + tmp[t] - v;
}

// ---------------- scatter: counting-sort, fused {point,vid} record ---------
__global__ void k_scatter(const unsigned int* __restrict__ vid,
                          unsigned int* __restrict__ cursor,
                          uint2* __restrict__ pv, int n) {
  int p = blockIdx.x * blockDim.x + threadIdx.x;
  if (p >= n) return;
  unsigned int v = vid[p];
  unsigned int pos = atomicAdd(&cursor[v], 1u);
  pv[pos] = uint2{(unsigned int)p, v};
}

// ---------------- zero-fill empty voxel output rows ----------------
__global__ void k_zero(const unsigned int* __restrict__ cnt,
                       float4* __restrict__ out4) {
  int tid = blockIdx.x * blockDim.x + threadIdx.x;  // kCL*16 threads
  int vox = tid >> 4;
  if (vox >= kCL) return;
  if (cnt[vox] == 0u) out4[tid] = float4{0.f, 0.f, 0.f, 0.f};
}

// ---------------- fused VFE ----------------
__global__ __launch_bounds__(256, 4) void k_fused(
    const float4* __restrict__ feat,
    const uint2* __restrict__ pv,
    const float* __restrict__ W1,
    const float* __restrict__ scale1, const float* __restrict__ shift1,
    const float* __restrict__ W2,
    const float* __restrict__ scale2, const float* __restrict__ shift2,
    float* __restrict__ out, int n) {
  __shared__ unsigned int gvid[128];   // vid window [i0n-1, i0n+126]
  __shared__ union {
    float Fraw[128][4];                // raw features (phases A..E)
    float Cst[4][16][20];              // per-wave GEMM2 C staging (loop)
  } u;
  __shared__ float Ft[11][NPmax];      // features, transposed (bcast reads)
  __shared__ unsigned short Ph[NPmax][72];  // pf1, bf16
  __shared__ unsigned short Vh[NPmax][72];  // per-slot vmax(pf1), bf16
  __shared__ int slot_of[NPmax];
  __shared__ int slot_start[NPmax + 1];
  __shared__ unsigned int slot_vox[NPmax];
  __shared__ int sA[NPmax + 2];        // voxel-aligned group boundaries
  __shared__ unsigned long long bmask[2];
  __shared__ int sNG;

  int t = threadIdx.x;
  int lane = t & 63, wv = t >> 6;
  long long i0n = (long long)blockIdx.x * P;

  // A: window load (sorted-order gather)
  if (t < 128) {
    long long pos = i0n - 1 + t;
    unsigned int v = 0xFFFFFFFFu;
    float4 f = float4{0.f, 0.f, 0.f, 0.f};
    if (pos >= 0 && pos < n) {
      uint2 e = pv[pos];
      v = e.y;
      f = feat[e.x];
    }
    gvid[t] = v;
    u.Fraw[t][0] = f.x; u.Fraw[t][1] = f.y;
    u.Fraw[t][2] = f.z; u.Fraw[t][3] = f.w;
  }
  __syncthreads();

  // B: every wave redundantly computes the voxel-complete range; waves 0,1
  //    ballot slot (voxel-run) boundaries.
  int s_off, np;
  {
    bool eq = (blockIdx.x > 0) && (gvid[1 + lane] == gvid[0]);
    unsigned long long m = __ballot(eq);
    s_off = (~m == 0ull) ? 64 : (__ffsll((long long)~m) - 1);
    unsigned int lastv = gvid[P];
    bool eq2 = (1 + P + lane < 128) && (lastv != 0xFFFFFFFFu) &&
               (gvid[1 + P + lane] == lastv);
    unsigned long long m2 = __ballot(eq2);
    int e_off = __ffsll((long long)~m2) - 1;  // lane63 false -> well-defined
    long long ecap = (long long)(P + e_off);
    if (ecap > n - i0n) ecap = n - i0n;
    np = (int)ecap - s_off;
    if (np > NPmax) np = NPmax;
    bool valid = (t < np);
    bool bf = valid && (t == 0 || gvid[1 + s_off + t] != gvid[s_off + t]);
    unsigned long long bm = __ballot(bf);
    if (lane == 0 && wv < 2) bmask[wv] = bm;
  }
  __syncthreads();
  if (np <= 0) return;

  // C: slot structure
  unsigned long long m0 = bmask[0], m1 = bmask[1];
  int ns = __popcll(m0) + __popcll(m1);
  if (t < np) {
    int j = t;
    int slot = (j < 64) ? (__popcll(m0 << (63 - j)) - 1)
                        : (__popcll(m0) + __popcll(m1 << (63 - (j - 64))) - 1);
    slot_of[j] = slot;
    bool bf = (j == 0) || (gvid[1 + s_off + j] != gvid[s_off + j]);
    if (bf) { slot_start[slot] = j; slot_vox[slot] = gvid[1 + s_off + j]; }
  }
  if (t == 0) slot_start[ns] = np;
  __syncthreads();

  // D: per-point features (own-slot mean recomputed per point) + group chain
  if (t < np) {
    int s = slot_of[t];
    int r0 = slot_start[s], r1 = slot_start[s + 1];
    float sx = 0.f, sy = 0.f, sz = 0.f;
    for (int j = r0; j < r1; ++j) {
      sx += u.Fraw[1 + s_off + j][0];
      sy += u.Fraw[1 + s_off + j][1];
      sz += u.Fraw[1 + s_off + j][2];
    }
    float rc = 1.0f / (float)(r1 - r0);
    int jw = 1 + s_off + t;
    float fx = u.Fraw[jw][0], fy = u.Fraw[jw][1];
    float fz = u.Fraw[jw][2], fr = u.Fraw[jw][3];
    unsigned int v = gvid[jw];
    unsigned int cx = v % (unsigned int)kCX;
    unsigned int cy = (v / (unsigned int)kCX) % (unsigned int)kCY;
    Ft[0][t] = fx; Ft[1][t] = fy; Ft[2][t] = fz; Ft[3][t] = fr;
    Ft[4][t] = fx - sx * rc;
    Ft[5][t] = fy - sy * rc;
    Ft[6][t] = fz - sz * rc;
    Ft[7][t] = fx - ((float)cx * kVX + kXOFF);
    Ft[8][t] = fy - ((float)cy * kVY + kYOFF);
    Ft[9][t] = fz - kZOFF;
    Ft[10][t] = sqrtf(fx * fx + fy * fy + fz * fz);
  }
  if (t == 255) {
    int g = 0, cur = 0;
    sA[0] = 0;
    while (cur < np) {
      int nxt;
      if (cur + 16 >= np) nxt = np;
      else {
        nxt = slot_start[slot_of[cur + 16]];
        if (nxt <= cur) nxt = cur + 16;  // >16-pt voxel guard
      }
      ++g; sA[g] = nxt; cur = nxt;
    }
    sNG = g;
  }
  __syncthreads();

  // E: GEMM1 on VALU, exact f32 (K=11). j is wave-uniform -> Ft broadcasts.
  {
    int col = t & 63;
    float w[11];
#pragma unroll
    for (int k = 0; k < 11; ++k) w[k] = W1[k * 64 + col];
    float s1 = scale1[col], sh1 = shift1[col];
    for (int j = wv; j < np; j += 4) {
      float acc = 0.f;
#pragma unroll
      for (int k = 0; k < 11; ++k) acc += Ft[k][j] * w[k];
      Ph[j][col] = f2bf(fmaxf(acc * s1 + sh1, 0.0f));
    }
  }
  __syncthreads();

  // F: per-slot vmax of pf1 (bf16>=0: u16 compare == value compare)
  {
    int col = t & 63;
    for (int s = wv; s < ns; s += 4) {
      int r0 = slot_start[s], r1 = slot_start[s + 1];
      unsigned short mx = 0;
      for (int j = r0; j < r1; ++j) {
        unsigned short x = Ph[j][col];
        if (x > mx) mx = x;
      }
      Vh[s][col] = mx;
    }
  }
  __syncthreads();

  // G: GEMM2 (MFMA, bf16 A x split-W2) — barrier-free group loop.
  int m = lane & 15, q = lane >> 4;
  int col = wv * 16 + m;
  BF8 b2h[4], b2l[4];
#pragma unroll
  for (int kb = 0; kb < 4; ++kb)
#pragma unroll
    for (int i = 0; i < 8; ++i)
      split_bf(W2[(kb * 32 + q * 8 + i) * 64 + col], b2h[kb].u[i],
               b2l[kb].u[i]);
  float s2 = scale2[col], sh2 = shift2[col];
  int ng = sNG;
  for (int g = 0; g < ng; ++g) {
    int base = sA[g], lim = sA[g + 1];
    int jj = base + m;
    if (jj > np - 1) jj = np - 1;  // pad rows (ignored in reduce)
    int sl = slot_of[jj];
    f32x4 c2 = {0.f, 0.f, 0.f, 0.f};
#pragma unroll
    for (int kb = 0; kb < 4; ++kb) {
      const unsigned short* ph = (kb < 2) ? &Ph[jj][kb * 32 + q * 8]
                                          : &Vh[sl][(kb - 2) * 32 + q * 8];
      BF8 a;
      *(ushort4*)&a.u[0] = *(const ushort4*)ph;
      *(ushort4*)&a.u[4] = *(const ushort4*)(ph + 4);
      c2 = __builtin_amdgcn_mfma_f32_16x16x32_bf16(a.v, b2h[kb].v, c2, 0, 0, 0);
      c2 = __builtin_amdgcn_mfma_f32_16x16x32_bf16(a.v, b2l[kb].v, c2, 0, 0, 0);
    }
    // per-wave private transpose (same-wave LDS RAW is in-order: no barrier)
#pragma unroll
    for (int r = 0; r < 4; ++r)
      u.Cst[wv][q * 4 + r][m] = fmaxf(c2[r] * s2 + sh2, 0.0f);
    int s_lo = slot_of[base], s_hi = slot_of[lim - 1];
    for (int s = s_lo + q; s <= s_hi; s += 4) {
      int r0 = slot_start[s], r1 = slot_start[s + 1];
      if (r1 > lim) r1 = lim;
      float mx = 0.f;
      for (int j = r0; j < r1; ++j)
        mx = fmaxf(mx, u.Cst[wv][j - base][m]);
      out[(size_t)slot_vox[s] * 64 + col] = mx;
    }
  }
}

extern "C" void kernel_launch(void* const* d_in, const int* in_sizes, int n_in,
                              void* d_out, int out_size, void* d_ws, size_t ws_size,
                              hipStream_t stream) {
  const float4* feat = (const float4*)d_in[0];
  const int4* coors = (const int4*)d_in[1];
  const float* W1 = (const float*)d_in[2];
  const float* scale1 = (const float*)d_in[3];
  const float* shift1 = (const float*)d_in[4];
  const float* W2 = (const float*)d_in[5];
  const float* scale2 = (const float*)d_in[6];
  const float* shift2 = (const float*)d_in[7];
  int n = in_sizes[0] / 4;  // 500000 points

  // Workspace (~8.6 MB): cnt | cursor | bsum | boff | vid[n] | pv[n] (uint2)
  unsigned int* cnt = (unsigned int*)d_ws;
  unsigned int* cursor = cnt + kCL;
  unsigned int* bsum = cursor + kCL;
  unsigned int* boff = bsum + 1104;
  unsigned int* vid = boff + 1104;
  uint2* pv = (uint2*)(vid + ((n + 1) & ~1));
  hipMemsetAsync(cnt, 0, (size_t)kCL * 4, stream);

  k_hist<<<(n + 255) / 256, 256, 0, stream>>>(coors, cnt, vid, n);
  k_scan1<<<NBLK, 256, 0, stream>>>(cnt, bsum);
  k_scan2<<<1, 256, 0, stream>>>(bsum, boff, NBLK);
  k_scan3<<<NBLK, 256, 0, stream>>>(cnt, boff, cursor);
  k_scatter<<<(n + 255) / 256, 256, 0, stream>>>(vid, cursor, pv, n);
  k_zero<<<kCL * 16 / 256, 256, 0, stream>>>(cnt, (float4*)d_out);
  k_fused<<<(n + P - 1) / P, 256, 0, stream>>>(
      feat, pv, W1, scale1, shift1, W2, scale2, shift2, (float*)d_out, n);
}